// Round 18
// baseline (575.312 us; speedup 1.0000x reference)
//
#include <hip/hip_runtime.h>
#include <math.h>

// 1/sqrt(1+1e-5) — eval BatchNorm with default stats
#define BNS 0.9999950000374997f

static inline int cdiv(int a, int b) { return (a + b - 1) / b; }

typedef short short8 __attribute__((ext_vector_type(8)));
typedef float f32x4 __attribute__((ext_vector_type(4)));
typedef unsigned int u32x4 __attribute__((ext_vector_type(4)));

__device__ __forceinline__ unsigned short f2bf(float f) {
    unsigned int u = __float_as_uint(f);
    u += 0x7fffu + ((u >> 16) & 1u);
    return (unsigned short)(u >> 16);
}
__device__ __forceinline__ float bf2f(unsigned short u) {
    return __uint_as_float(((unsigned int)u) << 16);
}

// bijective XCD swizzle (m204)
__device__ __forceinline__ int xcd_swz(int bid, int nwg) {
    int q = nwg >> 3, r = nwg & 7;
    int xcd = bid & 7;
    int idx = bid >> 3;
    return (xcd < r ? xcd * (q + 1) : r * (q + 1) + (xcd - r) * q) + idx;
}

// per-n element strides of the big NDHWC ushort buffer regions
#define U1 ((size_t)39304 * 48)   // 34^3 x 48ch
#define U2 ((size_t)46656 * 48)   // padded 36^3 x 48ch
#define U3 ((size_t)39304 * 32)   // 34^3 x 32ch

// ---------------- fused weight prep (one launch) ----------------
__device__ __forceinline__ void trw_one(const float* __restrict__ w,
                                        unsigned short* __restrict__ Bt,
                                        int CIN, int NCO, int i) {
    int cil = i & 31;
    int nn = (i >> 5) % NCO;
    int t = (i / (32 * NCO)) % 27;
    int c = i / (32 * NCO * 27);
    int ci = c * 32 + cil;
    Bt[i] = f2bf(ci < CIN ? w[(nn * CIN + ci) * 27 + t] : 0.f);
}
__device__ __forceinline__ void trc_one(const float* __restrict__ w,
                                        float* __restrict__ wT,
                                        int CIN, int COUT, int i) {
    int co = i % COUT;
    int tap = (i / COUT) % 27;
    int ci = i / (COUT * 27);
    wT[i] = w[(co * CIN + ci) * 27 + tap];
}

__global__ __launch_bounds__(256) void
k_prep(const float* __restrict__ wupt, const float* __restrict__ wupc,
       const float* __restrict__ wts2, const float* __restrict__ wb1a,
       const float* __restrict__ wb1b, const float* __restrict__ wpa,
       const float* __restrict__ wts1, const float* __restrict__ wpb,
       unsigned short* __restrict__ BtT, unsigned short* __restrict__ Bupc,
       unsigned short* __restrict__ Bts2, unsigned short* __restrict__ Bb1a,
       unsigned short* __restrict__ Bb1b, unsigned short* __restrict__ Bpa,
       float* __restrict__ wTts1, float* __restrict__ wTpb) {
    int i = blockIdx.x * 256 + threadIdx.x;
    if (i < 65536) {  // convT weights [tap][co][ci]
        int cil = i & 31, co = (i >> 5) & 31, tap = i >> 10;
        BtT[i] = f2bf(wupt[(cil * 32 + co) * 64 + tap]);
        return;
    }
    i -= 65536;
    if (i < 27648) { trw_one(wupc, Bupc, 32, 32, i); return; }
    i -= 27648;
    if (i < 13824) { trw_one(wts2, Bts2, 16, 16, i); return; }
    i -= 13824;
    if (i < 55296) { trw_one(wb1a, Bb1a, 48, 32, i); return; }
    i -= 55296;
    if (i < 27648) { trw_one(wb1b, Bb1b, 32, 32, i); return; }
    i -= 27648;
    if (i < 13824) { trw_one(wpa, Bpa, 32, 16, i); return; }
    i -= 13824;
    if (i < 432) { trc_one(wts1, wTts1, 1, 16, i); return; }
    i -= 432;
    if (i < 3456) { trc_one(wpb, wTpb, 16, 8, i); return; }
}

// prev [27][32][4096] fp32 NCDHW -> prevT [27][4096][32] bf16 NDHWC (LDS transpose)
__global__ __launch_bounds__(256) void k_tprev(const float* __restrict__ prev,
                                               unsigned short* __restrict__ out) {
    __shared__ float t32[32][65];
    int n = blockIdx.y;
    int p0 = blockIdx.x * 64;
    int tid = threadIdx.x;
    #pragma unroll
    for (int it = 0; it < 8; ++it) {
        int idx = it * 256 + tid;
        int ci = idx >> 6;
        int dp = idx & 63;
        t32[ci][dp] = prev[((size_t)n * 32 + ci) * 4096 + p0 + dp];
    }
    __syncthreads();
    int dp = tid >> 2;
    int cq = (tid & 3) * 8;
    u32x4 u;
    #pragma unroll
    for (int j = 0; j < 4; ++j) {
        u[j] = (unsigned int)f2bf(t32[cq + 2 * j][dp]) |
               ((unsigned int)f2bf(t32[cq + 2 * j + 1][dp]) << 16);
    }
    *(u32x4*)(out + ((size_t)n * 4096 + p0 + dp) * 32 + cq) = u;
}

// ---------------- ts1: carve tsdf block, replicate-pad-2, conv 1->16, relu(x*BNS) -> buf1 c32..47
__global__ __launch_bounds__(256) void k_ts1(const float* __restrict__ tsdf,
                                             const float* __restrict__ wT,
                                             unsigned short* __restrict__ buf1, int nbase) {
    int n = blockIdx.y;
    int ng = nbase + n;
    int a1 = ng / 9, b1 = (ng / 3) % 3, c1 = ng % 3;
    int s = blockIdx.x * 256 + threadIdx.x;
    if (s >= 39304) return;
    int z = s / (34 * 34);
    int r = s % (34 * 34);
    int y = r / 34;
    int x = r % 34;

    int base = (a1 * 32 * 96 + b1 * 32) * 96 + c1 * 32;
    int offs[27];
    #pragma unroll
    for (int kz = 0; kz < 3; ++kz) {
        int zz = z + kz - 2; zz = zz < 0 ? 0 : (zz > 31 ? 31 : zz);
        #pragma unroll
        for (int ky = 0; ky < 3; ++ky) {
            int yy = y + ky - 2; yy = yy < 0 ? 0 : (yy > 31 ? 31 : yy);
            #pragma unroll
            for (int kx = 0; kx < 3; ++kx) {
                int xx = x + kx - 2; xx = xx < 0 ? 0 : (xx > 31 ? 31 : xx);
                offs[(kz * 3 + ky) * 3 + kx] = zz * 9216 + yy * 96 + xx;
            }
        }
    }

    float acc[16];
    #pragma unroll
    for (int c = 0; c < 16; ++c) acc[c] = 0.f;

    const float* p = tsdf + base;
    #pragma unroll
    for (int t = 0; t < 27; ++t) {
        float v = p[offs[t]];
        const float* wp = wT + t * 16;
        #pragma unroll
        for (int co = 0; co < 16; ++co) acc[co] = fmaf(v, wp[co], acc[co]);
    }

    unsigned short* o = buf1 + (size_t)n * U1 + (size_t)s * 48 + 32;
    #pragma unroll
    for (int co = 0; co < 16; ++co) {
        float v = acc[co] * BNS;
        o[co] = f2bf(v > 0.f ? v : 0.f);
    }
}

// ---------------- LDS-staged MFMA implicit-GEMM 3^3 conv (R9 + T14 prefetch + T5 setprio) --
// WG tile = 2z x 4y x OUTD x (256 threads, 4 waves). Input tile (4z x 6y x XE) in LDS at
// 64 B/position. CH=2: chunk-1 loads issued before chunk-0 MFMAs (double reg buffer).
// MFMA tap cluster wrapped in s_setprio(1)/(0) — with the prefetch role-split, the CU
// scheduler favors MFMA-phase waves (T5 prerequisite satisfied per m218b).
// C/D: col=lane&15, row=(lane>>4)*4+rr [validated R4..R17].
template <int CSTRIDE, int CINOFF, int KRLOC, int CH, int NCO, int OCST, int OCOFF,
          int IND, int OUTD, int OD2, int OPAD, bool RELU>
__global__ __launch_bounds__(256) void
k_cl(const unsigned short* __restrict__ in, const unsigned short* __restrict__ Bt,
     unsigned short* __restrict__ out, size_t inNS, size_t outNS) {
    constexpr int TZ = 2, TY = 4;
    constexpr int XE = OUTD + 2;
    constexpr int XG = (OUTD + 15) / 16;
    constexpr int NSUB = (TZ * TY * XG) / 4;
    constexpr int NT = NCO / 16;
    constexpr int ZT = (OUTD + TZ - 1) / TZ;
    constexpr int YT = (OUTD + TY - 1) / TY;
    constexpr int POS = (TZ + 2) * (TY + 2) * XE;
    constexpr int ITER = (POS * 4 + 255) / 256;
    constexpr int NBUF = (CH > 1) ? 2 : 1;

    __shared__ __align__(16) unsigned char smem[POS * 64];

    int wg = xcd_swz(blockIdx.x, gridDim.x);
    int n = wg / (ZT * YT);
    int r0 = wg - n * (ZT * YT);
    int zt = r0 / YT, yt = r0 - zt * YT;
    int z0 = zt * TZ, y0 = yt * TY;

    int tid = threadIdx.x;
    int lane = tid & 63;
    int q = lane & 15, g = lane >> 4;
    int wv = tid >> 6;

    const unsigned char* inN = (const unsigned char*)(in + (size_t)n * inNS);

    int goff[ITER];
    #pragma unroll
    for (int it = 0; it < ITER; ++it) {
        int i = it * 256 + tid;
        int i2 = i < POS * 4 ? i : POS * 4 - 1;
        int slot = i2 & 3;
        int pos = i2 >> 2;
        int dx = pos % XE;
        int rm = pos / XE;
        int dy = rm % (TY + 2);
        int dz = rm / (TY + 2);
        int iz = z0 + dz; iz = iz < IND - 1 ? iz : IND - 1;
        int iy = y0 + dy; iy = iy < IND - 1 ? iy : IND - 1;
        goff[it] = (((iz * IND + iy) * IND + dx) * CSTRIDE + CINOFF) * 2 + slot * 16;
    }

    int posj[NSUB];
    #pragma unroll
    for (int j = 0; j < NSUB; ++j) {
        int s = wv * NSUB + j;
        int sz = s / (TY * XG);
        int rm = s - sz * (TY * XG);
        int sy = rm / XG;
        int sxg = rm - sy * XG;
        int x = sxg * 16 + q;
        x = x < OUTD ? x : OUTD - 1;
        posj[j] = (sz * (TY + 2) + sy) * XE + x;
    }

    f32x4 acc[NSUB][NT];
    #pragma unroll
    for (int j = 0; j < NSUB; ++j)
        #pragma unroll
        for (int nt = 0; nt < NT; ++nt)
            #pragma unroll
            for (int rr = 0; rr < 4; ++rr) acc[j][nt][rr] = 0.f;

    short8 tmp[NBUF][ITER];
    #pragma unroll
    for (int it = 0; it < ITER; ++it) {
        int i = it * 256 + tid;
        short8 v = {0, 0, 0, 0, 0, 0, 0, 0};
        if (i < POS * 4 && (i & 3) * 8 < KRLOC)
            v = *(const short8*)(inN + goff[it]);
        tmp[0][it] = v;
    }

    #pragma unroll
    for (int c = 0; c < CH; ++c) {
        if (c) __syncthreads();
        #pragma unroll
        for (int it = 0; it < ITER; ++it) {
            int i = it * 256 + tid;
            if (i < POS * 4) *(short8*)(smem + (size_t)i * 16) = tmp[c % NBUF][it];
        }
        __syncthreads();
        if (c + 1 < CH) {
            #pragma unroll
            for (int it = 0; it < ITER; ++it) {
                int i = it * 256 + tid;
                short8 v = {0, 0, 0, 0, 0, 0, 0, 0};
                if (i < POS * 4 && (c + 1) * 32 + (i & 3) * 8 < KRLOC)
                    v = *(const short8*)(inN + goff[it] + (c + 1) * 64);
                tmp[(c + 1) % NBUF][it] = v;
            }
        }
        const unsigned short* bc = Bt + (size_t)(c * 27) * NCO * 32 + (size_t)q * 32 + g * 8;
        __builtin_amdgcn_s_setprio(1);
        #pragma unroll
        for (int t = 0; t < 27; ++t) {
            const int kz = t / 9, ky = (t / 3) % 3, kx = t % 3;
            const int toff = ((kz * (TY + 2) + ky) * XE + kx) * 64 + g * 16;
            short8 bq[NT];
            #pragma unroll
            for (int nt = 0; nt < NT; ++nt)
                bq[nt] = *(const short8*)(bc + ((size_t)t * NCO + nt * 16) * 32);
            #pragma unroll
            for (int j = 0; j < NSUB; ++j) {
                short8 a = *(const short8*)(smem + posj[j] * 64 + toff);
                #pragma unroll
                for (int nt = 0; nt < NT; ++nt)
                    acc[j][nt] = __builtin_amdgcn_mfma_f32_16x16x32_bf16(a, bq[nt], acc[j][nt], 0, 0, 0);
            }
        }
        __builtin_amdgcn_s_setprio(0);
    }

    unsigned short* outN = out + (size_t)n * outNS;
    #pragma unroll
    for (int j = 0; j < NSUB; ++j) {
        int s = wv * NSUB + j;
        int sz = s / (TY * XG);
        int rm = s - sz * (TY * XG);
        int sy = rm / XG;
        int sxg = rm - sy * XG;
        int z = z0 + sz, y = y0 + sy;
        if (z < OUTD && y < OUTD) {
            #pragma unroll
            for (int rr = 0; rr < 4; ++rr) {
                int x = sxg * 16 + g * 4 + rr;
                if (x < OUTD) {
                    size_t ob = ((size_t)((z + OPAD) * OD2 + y + OPAD) * OD2 + (x + OPAD)) * OCST + OCOFF;
                    #pragma unroll
                    for (int nt = 0; nt < NT; ++nt) {
                        float v = acc[j][nt][rr] * BNS;
                        if (RELU) v = v > 0.f ? v : 0.f;
                        outN[ob + nt * 16 + q] = f2bf(v);
                    }
                }
            }
        }
    }
}

// ---------------- fused upc+ts2 at R9 tiling + T14 prefetch + T5 setprio ----------------
__global__ __launch_bounds__(256) void
k_cf(const unsigned short* __restrict__ in, const unsigned short* __restrict__ Bu,
     const unsigned short* __restrict__ Bts, unsigned short* __restrict__ out) {
    constexpr int TZ = 2, TY = 4, OUTD = 32, IND = 34, XE = 34, XG = 2;
    constexpr int NSUB = 4, ZT = 16, YT = 8;
    constexpr int POS = (TZ + 2) * (TY + 2) * XE;   // 816
    constexpr int ITER = (POS * 4 + 255) / 256;     // 13

    __shared__ __align__(16) unsigned char smem[POS * 64];

    int wg = xcd_swz(blockIdx.x, gridDim.x);
    int n = wg / (ZT * YT);
    int r0 = wg - n * (ZT * YT);
    int zt = r0 / YT, yt = r0 - zt * YT;
    int z0 = zt * TZ, y0 = yt * TY;

    int tid = threadIdx.x;
    int lane = tid & 63;
    int q = lane & 15, g = lane >> 4;
    int wv = tid >> 6;

    const unsigned char* inN = (const unsigned char*)(in + (size_t)n * U1);

    int goff[ITER];
    #pragma unroll
    for (int it = 0; it < ITER; ++it) {
        int i = it * 256 + tid;
        int i2 = i < POS * 4 ? i : POS * 4 - 1;
        int slot = i2 & 3;
        int pos = i2 >> 2;
        int dx = pos % XE;
        int rm = pos / XE;
        int dy = rm % (TY + 2);
        int dz = rm / (TY + 2);
        int iz = z0 + dz; iz = iz < IND - 1 ? iz : IND - 1;
        int iy = y0 + dy; iy = iy < IND - 1 ? iy : IND - 1;
        goff[it] = ((iz * IND + iy) * IND + dx) * 96 + slot * 16;
    }

    int posj[NSUB];
    #pragma unroll
    for (int j = 0; j < NSUB; ++j) {
        int s = wv * NSUB + j;
        int sz = s / (TY * XG);
        int rm = s - sz * (TY * XG);
        int sy = rm / XG;
        int sxg = rm - sy * XG;
        int x = sxg * 16 + q;
        x = x < OUTD ? x : OUTD - 1;
        posj[j] = (sz * (TY + 2) + sy) * XE + x;
    }

    f32x4 accU[NSUB][2];
    f32x4 accT[NSUB];
    #pragma unroll
    for (int j = 0; j < NSUB; ++j) {
        #pragma unroll
        for (int rr = 0; rr < 4; ++rr) {
            accU[j][0][rr] = 0.f; accU[j][1][rr] = 0.f; accT[j][rr] = 0.f;
        }
    }

    short8 tmp[2][ITER];
    #pragma unroll
    for (int it = 0; it < ITER; ++it) {
        int i = it * 256 + tid;
        short8 v = {0, 0, 0, 0, 0, 0, 0, 0};
        if (i < POS * 4 && (i & 3) * 8 < 48)
            v = *(const short8*)(inN + goff[it]);
        tmp[0][it] = v;
    }

    #pragma unroll
    for (int c = 0; c < 2; ++c) {
        if (c) __syncthreads();
        #pragma unroll
        for (int it = 0; it < ITER; ++it) {
            int i = it * 256 + tid;
            if (i < POS * 4) *(short8*)(smem + (size_t)i * 16) = tmp[c][it];
        }
        __syncthreads();
        if (c == 0) {
            #pragma unroll
            for (int it = 0; it < ITER; ++it) {
                int i = it * 256 + tid;
                short8 v = {0, 0, 0, 0, 0, 0, 0, 0};
                if (i < POS * 4 && 32 + (i & 3) * 8 < 48)
                    v = *(const short8*)(inN + goff[it] + 64);
                tmp[1][it] = v;
            }
            const unsigned short* bc = Bu + (size_t)q * 32 + g * 8;
            __builtin_amdgcn_s_setprio(1);
            #pragma unroll
            for (int t = 0; t < 27; ++t) {
                const int kz = t / 9, ky = (t / 3) % 3, kx = t % 3;
                const int toff = ((kz * (TY + 2) + ky) * XE + kx) * 64 + g * 16;
                short8 b0 = *(const short8*)(bc + ((size_t)t * 32) * 32);
                short8 b1 = *(const short8*)(bc + ((size_t)t * 32 + 16) * 32);
                #pragma unroll
                for (int j = 0; j < NSUB; ++j) {
                    short8 a = *(const short8*)(smem + posj[j] * 64 + toff);
                    accU[j][0] = __builtin_amdgcn_mfma_f32_16x16x32_bf16(a, b0, accU[j][0], 0, 0, 0);
                    accU[j][1] = __builtin_amdgcn_mfma_f32_16x16x32_bf16(a, b1, accU[j][1], 0, 0, 0);
                }
            }
            __builtin_amdgcn_s_setprio(0);
        } else {
            const unsigned short* bc = Bts + (size_t)q * 32 + g * 8;
            __builtin_amdgcn_s_setprio(1);
            #pragma unroll
            for (int t = 0; t < 27; ++t) {
                const int kz = t / 9, ky = (t / 3) % 3, kx = t % 3;
                const int toff = ((kz * (TY + 2) + ky) * XE + kx) * 64 + g * 16;
                short8 b0 = *(const short8*)(bc + ((size_t)t * 16) * 32);
                #pragma unroll
                for (int j = 0; j < NSUB; ++j) {
                    short8 a = *(const short8*)(smem + posj[j] * 64 + toff);
                    accT[j] = __builtin_amdgcn_mfma_f32_16x16x32_bf16(a, b0, accT[j], 0, 0, 0);
                }
            }
            __builtin_amdgcn_s_setprio(0);
        }
    }

    unsigned short* outN = out + (size_t)n * U2;
    #pragma unroll
    for (int j = 0; j < NSUB; ++j) {
        int s = wv * NSUB + j;
        int sz = s / (TY * XG);
        int rm = s - sz * (TY * XG);
        int sy = rm / XG;
        int sxg = rm - sy * XG;
        int z = z0 + sz, y = y0 + sy;
        if (z < OUTD && y < OUTD) {
            #pragma unroll
            for (int rr = 0; rr < 4; ++rr) {
                int x = sxg * 16 + g * 4 + rr;
                if (x < OUTD) {
                    size_t ob = ((size_t)((z + 2) * 36 + y + 2) * 36 + (x + 2)) * 48;
                    outN[ob + q]      = f2bf(accU[j][0][rr] * BNS);
                    outN[ob + 16 + q] = f2bf(accU[j][1][rr] * BNS);
                    outN[ob + 32 + q] = f2bf(accT[j][rr] * BNS);
                }
            }
        }
    }
}

// ---------------- replicate-pad shell fill for padded buf2 (36^3 x 48ch) ----------------
__global__ __launch_bounds__(256) void k_pad(unsigned short* __restrict__ buf2, int ncnt) {
    int i = blockIdx.x * 256 + threadIdx.x;
    int total = ncnt * 46656 * 6;
    if (i >= total) return;
    int slot = i % 6;
    int pos = (i / 6) % 46656;
    int nl = i / (6 * 46656);
    int x = pos % 36, y = (pos / 36) % 36, z = pos / 1296;
    if (x >= 2 && x < 34 && y >= 2 && y < 34 && z >= 2 && z < 34) return;
    int sx = x < 2 ? 2 : (x > 33 ? 33 : x);
    int sy = y < 2 ? 2 : (y > 33 ? 33 : y);
    int sz = z < 2 ? 2 : (z > 33 ? 33 : z);
    int src = (sz * 36 + sy) * 36 + sx;
    unsigned short* bn = buf2 + (size_t)nl * U2;
    *(u32x4*)(bn + (size_t)pos * 48 + slot * 8) =
        *(const u32x4*)(bn + (size_t)src * 48 + slot * 8);
}

// ---------------- convT as MFMA (LDS-staged): prevT -> buf1 c0..31 ----
__global__ __launch_bounds__(192) void
k_cT(const unsigned short* __restrict__ prevT, const unsigned short* __restrict__ Bt,
     unsigned short* __restrict__ buf1, int nbase) {
    constexpr int XE = 19, YS = 5, S = 2 * YS * XE;
    constexpr int MT = 68;

    __shared__ __align__(16) unsigned char smem[S * 80];

    int n = blockIdx.z;
    int ng = nbase + n;
    int q = blockIdx.y;
    int px = q & 1, py = (q >> 1) & 1, pz = q >> 2;
    int bt = blockIdx.x;
    int yt = bt % 5, z = bt / 5;
    int ty0 = yt * 4;

    int tid = threadIdx.x;
    int lane = tid & 63;
    int g = lane >> 4;
    int wv = tid >> 6;

    int mb = wv * 32 + (lane & 15);
    int m0 = mb < MT ? mb : MT - 1;
    int m1 = (mb + 16) < MT ? (mb + 16) : MT - 1;
    int dy0 = m0 / 17, x0 = m0 - dy0 * 17;
    int dy1 = m1 / 17, x1 = m1 - dy1 * 17;
    int pb0 = (dy0 * XE + x0) * 80 + g * 16;
    int pb1 = (dy1 * XE + x1) * 80 + g * 16;

    const unsigned short* inN = prevT + (size_t)ng * 4096 * 32;

    for (int i = tid; i < S * 4; i += 192) {
        int pos = i >> 2, slot = i & 3;
        int dz = pos / (YS * XE);
        int rem = pos - dz * (YS * XE);
        int dyy = rem / XE;
        int ix = rem - dyy * XE;
        int iz = z - 1 + dz;
        int iy = ty0 - 1 + dyy;
        int ixx = ix - 1;
        u32x4 v = {0u, 0u, 0u, 0u};
        if ((unsigned)iz < 16u && (unsigned)iy < 16u && (unsigned)ixx < 16u) {
            v = *(const u32x4*)(inN + ((size_t)(iz * 16 + iy) * 16 + ixx) * 32 + slot * 8);
        }
        *(u32x4*)(smem + pos * 80 + slot * 16) = v;
    }
    __syncthreads();

    int kz0 = 1 - pz, ky0 = 1 - py, kx0 = 1 - px;

    f32x4 acc[2][2];
    #pragma unroll
    for (int s2 = 0; s2 < 2; ++s2)
        #pragma unroll
        for (int nt = 0; nt < 2; ++nt)
            #pragma unroll
            for (int rr = 0; rr < 4; ++rr) acc[s2][nt][rr] = 0.f;

    #pragma unroll
    for (int cz = 0; cz < 2; ++cz)
        #pragma unroll
        for (int cy = 0; cy < 2; ++cy)
            #pragma unroll
            for (int cx = 0; cx < 2; ++cx) {
                int toff = ((cz * YS + cy) * XE + cx) * 80;
                int tapg = (((kz0 + 2 * cz) * 4 + (ky0 + 2 * cy)) * 4 + (kx0 + 2 * cx));
                const unsigned short* bb =
                    Bt + ((size_t)tapg * 32 + (lane & 15)) * 32 + g * 8;
                short8 a0 = *(const short8*)(smem + pb0 + toff);
                short8 a1 = *(const short8*)(smem + pb1 + toff);
                #pragma unroll
                for (int nt = 0; nt < 2; ++nt) {
                    short8 bf = *(const short8*)(bb + (size_t)nt * 16 * 32);
                    acc[0][nt] = __builtin_amdgcn_mfma_f32_16x16x32_bf16(a0, bf, acc[0][nt], 0, 0, 0);
                    acc[1][nt] = __builtin_amdgcn_mfma_f32_16x16x32_bf16(a1, bf, acc[1][nt], 0, 0, 0);
                }
            }

    unsigned short* outN = buf1 + (size_t)n * U1;
    int co0 = lane & 15;
    #pragma unroll
    for (int sub = 0; sub < 2; ++sub) {
        #pragma unroll
        for (int rr = 0; rr < 4; ++rr) {
            int m = wv * 32 + sub * 16 + g * 4 + rr;
            if (m < MT) {
                int dy = m / 17, tx = m - dy * 17;
                if (ty0 + dy < 17) {
                    int oz = 2 * z + pz, oy = 2 * (ty0 + dy) + py, ox = 2 * tx + px;
                    size_t ob = ((size_t)(oz * 34 + oy) * 34 + ox) * 48;
                    #pragma unroll
                    for (int nt = 0; nt < 2; ++nt) {
                        float v = acc[sub][nt][rr] * BNS;
                        outN[ob + nt * 16 + co0] = f2bf(v > 0.f ? v : 0.f);
                    }
                }
            }
        }
    }
}

// ---------------- maxpool3 (pa out [30^3][16] bf16, region stride U2) -> P1 fp32 NCDHW ----
__global__ __launch_bounds__(256) void k_pool3(const unsigned short* __restrict__ pa,
                                               float* __restrict__ out,
                                               int nbase, int ncnt) {
    int i = blockIdx.x * 256 + threadIdx.x;
    if (i >= ncnt * 16000) return;
    int c = i & 15;
    int rest = i >> 4;
    int x = rest % 10;
    int y = (rest / 10) % 10;
    int z = (rest / 100) % 10;
    int nl = rest / 1000;
    const unsigned short* p = pa + (size_t)nl * U2;
    float m = -INFINITY;
    #pragma unroll
    for (int dz = 0; dz < 3; ++dz)
        #pragma unroll
        for (int dy = 0; dy < 3; ++dy)
            #pragma unroll
            for (int dx = 0; dx < 3; ++dx)
                m = fmaxf(m, bf2f(p[((size_t)((3 * z + dz) * 30 + 3 * y + dy) * 30 +
                                    (3 * x + dx)) * 16 + c]));
    out[((size_t)(nbase + nl) * 16 + c) * 1000 + (z * 100 + y * 10 + x)] = m;
}

// ---------------- small fp32 conv for pb ----------------
template <int CIN, int COUT, int IND, int OUTD>
__global__ __launch_bounds__(256) void k_conv3(const float* __restrict__ in,
                                               const float* __restrict__ wT,
                                               float* __restrict__ out) {
    constexpr int IN3 = IND * IND * IND;
    constexpr int OD3 = OUTD * OUTD * OUTD;
    int n = blockIdx.y;
    int s = blockIdx.x * 256 + threadIdx.x;
    if (s >= OD3) return;
    int z = s / (OUTD * OUTD);
    int r = s % (OUTD * OUTD);
    int y = r / OUTD;
    int x = r % OUTD;

    int offs[27];
    #pragma unroll
    for (int kz = 0; kz < 3; ++kz)
        #pragma unroll
        for (int ky = 0; ky < 3; ++ky)
            #pragma unroll
            for (int kx = 0; kx < 3; ++kx)
                offs[(kz * 3 + ky) * 3 + kx] = ((z + kz) * IND + y + ky) * IND + x + kx;

    float acc[COUT];
    #pragma unroll
    for (int c = 0; c < COUT; ++c) acc[c] = 0.f;

    const float* inN = in + (size_t)n * CIN * IN3;
    for (int ci = 0; ci < CIN; ++ci) {
        const float* pc = inN + (size_t)ci * IN3;
        const float* wci = wT + ci * 27 * COUT;
        #pragma unroll
        for (int t = 0; t < 27; ++t) {
            float v = pc[offs[t]];
            const float* wp = wci + t * COUT;
            #pragma unroll
            for (int co = 0; co < COUT; ++co) acc[co] = fmaf(v, wp[co], acc[co]);
        }
    }

    float* o = out + (size_t)n * COUT * OD3 + s;
    #pragma unroll
    for (int co = 0; co < COUT; ++co) {
        float v = acc[co] * BNS;
        o[(size_t)co * OD3] = v > 0.f ? v : 0.f;
    }
}

// ---------------- maxpool4 + linear + softmax + threshold ----------------
__global__ __launch_bounds__(64) void k_final(const float* __restrict__ p2,
                                              const float* __restrict__ wlin,
                                              const float* __restrict__ blin,
                                              float* __restrict__ dout) {
    int n = blockIdx.x;
    int t = threadIdx.x;
    int c = t >> 3, dz = (t >> 2) & 1, dy = (t >> 1) & 1, dx = t & 1;
    const float* p = p2 + ((size_t)n * 8 + c) * 512;
    float m = -INFINITY;
    #pragma unroll
    for (int iz = 0; iz < 4; ++iz)
        #pragma unroll
        for (int iy = 0; iy < 4; ++iy)
            #pragma unroll
            for (int ix = 0; ix < 4; ++ix)
                m = fmaxf(m, p[((dz * 4 + iz) * 8 + dy * 4 + iy) * 8 + dx * 4 + ix]);
    __shared__ float h[64];
    __shared__ float lg[3];
    h[t] = m;
    __syncthreads();
    if (t < 3) {
        float acc = blin[t];
        for (int k = 0; k < 64; ++k) acc += h[k] * wlin[t * 64 + k];
        lg[t] = acc;
    }
    __syncthreads();
    if (t == 0) {
        float mx = fmaxf(fmaxf(lg[0], lg[1]), lg[2]);
        float e0 = expf(lg[0] - mx), e1 = expf(lg[1] - mx), e2 = expf(lg[2] - mx);
        float inv = 1.f / (e0 + e1 + e2);
        dout[n * 3 + 0] = e0 * inv;
        dout[n * 3 + 1] = e1 * inv;
        dout[n * 3 + 2] = e2 * inv;
        dout[81 + n] = (e2 * inv) > 0.1f ? 1.0f : 0.0f;
    }
}

extern "C" void kernel_launch(void* const* d_in, const int* in_sizes, int n_in,
                              void* d_out, int out_size, void* d_ws, size_t ws_size,
                              hipStream_t stream) {
    const float* tsdf  = (const float*)d_in[0];
    const float* prev  = (const float*)d_in[1];
    const float* w_upt = (const float*)d_in[2];
    const float* w_upc = (const float*)d_in[3];
    const float* w_ts1 = (const float*)d_in[4];
    const float* w_ts2 = (const float*)d_in[5];
    const float* w_b1a = (const float*)d_in[6];
    const float* w_b1b = (const float*)d_in[7];
    const float* w_pa  = (const float*)d_in[8];
    const float* w_pb  = (const float*)d_in[9];
    const float* w_lin = (const float*)d_in[10];
    const float* b_lin = (const float*)d_in[11];
    float* dout = (float*)d_out;

    char* base = (char*)d_ws;
    size_t off = 0;
    auto alB = [&](size_t bytes) {
        off = (off + 255) & ~(size_t)255;
        void* p = base + off;
        off += bytes;
        return p;
    };

    float* P1      = (float*)alB((size_t)27 * 16 * 1000 * 4);
    float* P2      = (float*)alB((size_t)27 * 8 * 512 * 4);
    float* wT_ts1  = (float*)alB(27 * 16 * 4);
    float* wT_pb   = (float*)alB((size_t)16 * 27 * 8 * 4);
    unsigned short* prevT   = (unsigned short*)alB((size_t)27 * 4096 * 32 * 2);
    unsigned short* BtT_upt = (unsigned short*)alB((size_t)64 * 32 * 32 * 2);
    unsigned short* Bt_upc  = (unsigned short*)alB((size_t)27 * 32 * 32 * 2);
    unsigned short* Bt_ts2  = (unsigned short*)alB((size_t)27 * 16 * 32 * 2);
    unsigned short* Bt_b1a  = (unsigned short*)alB((size_t)2 * 27 * 32 * 32 * 2);
    unsigned short* Bt_b1b  = (unsigned short*)alB((size_t)27 * 32 * 32 * 2);
    unsigned short* Bt_pa   = (unsigned short*)alB((size_t)27 * 16 * 32 * 2);

    size_t fixed = (off + 255) & ~(size_t)255;
    size_t per_block = (U1 + U2 + U3) * 2 + 768;
    size_t avail = ws_size > fixed ? ws_size - fixed : 0;
    int NB = (int)(avail / per_block);
    if (NB > 27) NB = 27;
    if (NB < 1) NB = 1;

    unsigned short* buf1 = (unsigned short*)alB((size_t)NB * U1 * 2);
    unsigned short* buf2 = (unsigned short*)alB((size_t)NB * U2 * 2);
    unsigned short* buf3 = (unsigned short*)alB((size_t)NB * U3 * 2);

    // fused weight prep (one launch) + prev transpose
    k_prep<<<cdiv(207664, 256), 256, 0, stream>>>(
        w_upt, w_upc, w_ts2, w_b1a, w_b1b, w_pa, w_ts1, w_pb,
        BtT_upt, Bt_upc, Bt_ts2, Bt_b1a, Bt_b1b, Bt_pa, wT_ts1, wT_pb);
    k_tprev<<<dim3(64, 27), 256, 0, stream>>>(prev, prevT);

    for (int n0 = 0; n0 < 27; n0 += NB) {
        int nc = 27 - n0 < NB ? 27 - n0 : NB;

        // producers into buf1 [34^3][48]
        k_cT<<<dim3(17 * 5, 8, nc), 192, 0, stream>>>(prevT, BtT_upt, buf1, n0);
        k_ts1<<<dim3(cdiv(39304, 256), nc), 256, 0, stream>>>(tsdf, wT_ts1, buf1, n0);

        // fused upc+ts2 into padded buf2 interior [36^3][48] at +2
        k_cf<<<nc * 16 * 8, 256, 0, stream>>>(buf1, Bt_upc, Bt_ts2, buf2);

        // replicate-pad shell of buf2
        k_pad<<<cdiv(nc * 46656 * 6, 256), 256, 0, stream>>>(buf2, nc);

        // b1a: padded buf2 (48ch, relu) -> buf3 [34^3][32]
        k_cl<48, 0, 48, 2, 32, 32, 0, 36, 34, 34, 0, true>
            <<<nc * 17 * 9, 256, 0, stream>>>(buf2, Bt_b1a, buf3, U2, U3);

        // b1b: buf3 -> feat [32^3][32] (into buf1 region)
        k_cl<32, 0, 32, 1, 32, 32, 0, 34, 32, 32, 0, false>
            <<<nc * 16 * 8, 256, 0, stream>>>(buf3, Bt_b1b, buf1, U3, U1);

        // pa: feat -> [30^3][16] (into buf2 region), relu
        k_cl<32, 0, 32, 1, 16, 16, 0, 32, 30, 30, 0, true>
            <<<nc * 15 * 8, 256, 0, stream>>>(buf1, Bt_pa, buf2, U1, U2);

        // pool3 into global P1 (fp32 NCDHW)
        k_pool3<<<cdiv(nc * 16000, 256), 256, 0, stream>>>(buf2, P1, n0, nc);
    }

    // tail
    k_conv3<16, 8, 10, 8><<<dim3(cdiv(512, 256), 27), 256, 0, stream>>>(P1, wT_pb, P2);
    k_final<<<27, 64, 0, stream>>>(P2, w_lin, b_lin, dout);
}

// Round 19
// 570.578 us; speedup vs baseline: 1.0083x; 1.0083x over previous
//
#include <hip/hip_runtime.h>
#include <math.h>

// 1/sqrt(1+1e-5) — eval BatchNorm with default stats
#define BNS 0.9999950000374997f

static inline int cdiv(int a, int b) { return (a + b - 1) / b; }

typedef short short8 __attribute__((ext_vector_type(8)));
typedef float f32x4 __attribute__((ext_vector_type(4)));
typedef unsigned int u32x4 __attribute__((ext_vector_type(4)));

__device__ __forceinline__ unsigned short f2bf(float f) {
    unsigned int u = __float_as_uint(f);
    u += 0x7fffu + ((u >> 16) & 1u);
    return (unsigned short)(u >> 16);
}
__device__ __forceinline__ float bf2f(unsigned short u) {
    return __uint_as_float(((unsigned int)u) << 16);
}

// bijective XCD swizzle (m204)
__device__ __forceinline__ int xcd_swz(int bid, int nwg) {
    int q = nwg >> 3, r = nwg & 7;
    int xcd = bid & 7;
    int idx = bid >> 3;
    return (xcd < r ? xcd * (q + 1) : r * (q + 1) + (xcd - r) * q) + idx;
}

// per-n element strides of the big NDHWC ushort buffer regions
#define U1 ((size_t)39304 * 48)   // 34^3 x 48ch
#define U2 ((size_t)46656 * 48)   // padded 36^3 x 48ch
#define U3 ((size_t)39304 * 32)   // 34^3 x 32ch

// ---------------- fused weight prep (one launch) ----------------
__device__ __forceinline__ void trw_one(const float* __restrict__ w,
                                        unsigned short* __restrict__ Bt,
                                        int CIN, int NCO, int i) {
    int cil = i & 31;
    int nn = (i >> 5) % NCO;
    int t = (i / (32 * NCO)) % 27;
    int c = i / (32 * NCO * 27);
    int ci = c * 32 + cil;
    Bt[i] = f2bf(ci < CIN ? w[(nn * CIN + ci) * 27 + t] : 0.f);
}
__device__ __forceinline__ void trc_one(const float* __restrict__ w,
                                        float* __restrict__ wT,
                                        int CIN, int COUT, int i) {
    int co = i % COUT;
    int tap = (i / COUT) % 27;
    int ci = i / (COUT * 27);
    wT[i] = w[(co * CIN + ci) * 27 + tap];
}

__global__ __launch_bounds__(256) void
k_prep(const float* __restrict__ wupt, const float* __restrict__ wupc,
       const float* __restrict__ wts2, const float* __restrict__ wb1a,
       const float* __restrict__ wb1b, const float* __restrict__ wpa,
       const float* __restrict__ wts1, const float* __restrict__ wpb,
       unsigned short* __restrict__ BtT, unsigned short* __restrict__ Bupc,
       unsigned short* __restrict__ Bts2, unsigned short* __restrict__ Bb1a,
       unsigned short* __restrict__ Bb1b, unsigned short* __restrict__ Bpa,
       float* __restrict__ wTts1, float* __restrict__ wTpb) {
    int i = blockIdx.x * 256 + threadIdx.x;
    if (i < 65536) {  // convT weights [tap][co][ci]
        int cil = i & 31, co = (i >> 5) & 31, tap = i >> 10;
        BtT[i] = f2bf(wupt[(cil * 32 + co) * 64 + tap]);
        return;
    }
    i -= 65536;
    if (i < 27648) { trw_one(wupc, Bupc, 32, 32, i); return; }
    i -= 27648;
    if (i < 13824) { trw_one(wts2, Bts2, 16, 16, i); return; }
    i -= 13824;
    if (i < 55296) { trw_one(wb1a, Bb1a, 48, 32, i); return; }
    i -= 55296;
    if (i < 27648) { trw_one(wb1b, Bb1b, 32, 32, i); return; }
    i -= 27648;
    if (i < 13824) { trw_one(wpa, Bpa, 32, 16, i); return; }
    i -= 13824;
    if (i < 432) { trc_one(wts1, wTts1, 1, 16, i); return; }
    i -= 432;
    if (i < 3456) { trc_one(wpb, wTpb, 16, 8, i); return; }
}

// prev [27][32][4096] fp32 NCDHW -> prevT [27][4096][32] bf16 NDHWC (LDS transpose)
__global__ __launch_bounds__(256) void k_tprev(const float* __restrict__ prev,
                                               unsigned short* __restrict__ out) {
    __shared__ float t32[32][65];
    int n = blockIdx.y;
    int p0 = blockIdx.x * 64;
    int tid = threadIdx.x;
    #pragma unroll
    for (int it = 0; it < 8; ++it) {
        int idx = it * 256 + tid;
        int ci = idx >> 6;
        int dp = idx & 63;
        t32[ci][dp] = prev[((size_t)n * 32 + ci) * 4096 + p0 + dp];
    }
    __syncthreads();
    int dp = tid >> 2;
    int cq = (tid & 3) * 8;
    u32x4 u;
    #pragma unroll
    for (int j = 0; j < 4; ++j) {
        u[j] = (unsigned int)f2bf(t32[cq + 2 * j][dp]) |
               ((unsigned int)f2bf(t32[cq + 2 * j + 1][dp]) << 16);
    }
    *(u32x4*)(out + ((size_t)n * 4096 + p0 + dp) * 32 + cq) = u;
}

// ---------------- ts1: carve tsdf block, replicate-pad-2, conv 1->16, relu(x*BNS) -> buf1 c32..47
__global__ __launch_bounds__(256) void k_ts1(const float* __restrict__ tsdf,
                                             const float* __restrict__ wT,
                                             unsigned short* __restrict__ buf1, int nbase) {
    int n = blockIdx.y;
    int ng = nbase + n;
    int a1 = ng / 9, b1 = (ng / 3) % 3, c1 = ng % 3;
    int s = blockIdx.x * 256 + threadIdx.x;
    if (s >= 39304) return;
    int z = s / (34 * 34);
    int r = s % (34 * 34);
    int y = r / 34;
    int x = r % 34;

    int base = (a1 * 32 * 96 + b1 * 32) * 96 + c1 * 32;
    int offs[27];
    #pragma unroll
    for (int kz = 0; kz < 3; ++kz) {
        int zz = z + kz - 2; zz = zz < 0 ? 0 : (zz > 31 ? 31 : zz);
        #pragma unroll
        for (int ky = 0; ky < 3; ++ky) {
            int yy = y + ky - 2; yy = yy < 0 ? 0 : (yy > 31 ? 31 : yy);
            #pragma unroll
            for (int kx = 0; kx < 3; ++kx) {
                int xx = x + kx - 2; xx = xx < 0 ? 0 : (xx > 31 ? 31 : xx);
                offs[(kz * 3 + ky) * 3 + kx] = zz * 9216 + yy * 96 + xx;
            }
        }
    }

    float acc[16];
    #pragma unroll
    for (int c = 0; c < 16; ++c) acc[c] = 0.f;

    const float* p = tsdf + base;
    #pragma unroll
    for (int t = 0; t < 27; ++t) {
        float v = p[offs[t]];
        const float* wp = wT + t * 16;
        #pragma unroll
        for (int co = 0; co < 16; ++co) acc[co] = fmaf(v, wp[co], acc[co]);
    }

    unsigned short* o = buf1 + (size_t)n * U1 + (size_t)s * 48 + 32;
    #pragma unroll
    for (int co = 0; co < 16; ++co) {
        float v = acc[co] * BNS;
        o[co] = f2bf(v > 0.f ? v : 0.f);
    }
}

// ---------------- LDS-staged MFMA implicit-GEMM 3^3 conv (R9 structure + T14 prefetch) ------
// WG tile = 2z x 4y x OUTD x (256 threads, 4 waves). Input tile (4z x 6y x XE) in LDS at
// 64 B/position. For CH=2, chunk-1 global loads are ISSUED before chunk-0's MFMA block
// (double register buffer; latency hides under 27-tap compute). KRLOC zero-fills padded K.
// C/D: col=lane&15, row=(lane>>4)*4+rr [validated R4..R18].
template <int CSTRIDE, int CINOFF, int KRLOC, int CH, int NCO, int OCST, int OCOFF,
          int IND, int OUTD, int OD2, int OPAD, bool RELU>
__global__ __launch_bounds__(256) void
k_cl(const unsigned short* __restrict__ in, const unsigned short* __restrict__ Bt,
     unsigned short* __restrict__ out, size_t inNS, size_t outNS) {
    constexpr int TZ = 2, TY = 4;
    constexpr int XE = OUTD + 2;
    constexpr int XG = (OUTD + 15) / 16;
    constexpr int NSUB = (TZ * TY * XG) / 4;
    constexpr int NT = NCO / 16;
    constexpr int ZT = (OUTD + TZ - 1) / TZ;
    constexpr int YT = (OUTD + TY - 1) / TY;
    constexpr int POS = (TZ + 2) * (TY + 2) * XE;
    constexpr int ITER = (POS * 4 + 255) / 256;
    constexpr int NBUF = (CH > 1) ? 2 : 1;

    __shared__ __align__(16) unsigned char smem[POS * 64];

    int wg = xcd_swz(blockIdx.x, gridDim.x);
    int n = wg / (ZT * YT);
    int r0 = wg - n * (ZT * YT);
    int zt = r0 / YT, yt = r0 - zt * YT;
    int z0 = zt * TZ, y0 = yt * TY;

    int tid = threadIdx.x;
    int lane = tid & 63;
    int q = lane & 15, g = lane >> 4;
    int wv = tid >> 6;

    const unsigned char* inN = (const unsigned char*)(in + (size_t)n * inNS);

    // per-it global byte offset (chunk-invariant) + slot id
    int goff[ITER];
    #pragma unroll
    for (int it = 0; it < ITER; ++it) {
        int i = it * 256 + tid;
        int i2 = i < POS * 4 ? i : POS * 4 - 1;
        int slot = i2 & 3;
        int pos = i2 >> 2;
        int dx = pos % XE;
        int rm = pos / XE;
        int dy = rm % (TY + 2);
        int dz = rm / (TY + 2);
        int iz = z0 + dz; iz = iz < IND - 1 ? iz : IND - 1;
        int iy = y0 + dy; iy = iy < IND - 1 ? iy : IND - 1;
        goff[it] = (((iz * IND + iy) * IND + dx) * CSTRIDE + CINOFF) * 2 + slot * 16;
    }

    int posj[NSUB];
    #pragma unroll
    for (int j = 0; j < NSUB; ++j) {
        int s = wv * NSUB + j;
        int sz = s / (TY * XG);
        int rm = s - sz * (TY * XG);
        int sy = rm / XG;
        int sxg = rm - sy * XG;
        int x = sxg * 16 + q;
        x = x < OUTD ? x : OUTD - 1;
        posj[j] = (sz * (TY + 2) + sy) * XE + x;
    }

    f32x4 acc[NSUB][NT];
    #pragma unroll
    for (int j = 0; j < NSUB; ++j)
        #pragma unroll
        for (int nt = 0; nt < NT; ++nt)
            #pragma unroll
            for (int rr = 0; rr < 4; ++rr) acc[j][nt][rr] = 0.f;

    short8 tmp[NBUF][ITER];
    // prologue: load chunk 0
    #pragma unroll
    for (int it = 0; it < ITER; ++it) {
        int i = it * 256 + tid;
        short8 v = {0, 0, 0, 0, 0, 0, 0, 0};
        if (i < POS * 4 && (i & 3) * 8 < KRLOC)
            v = *(const short8*)(inN + goff[it]);
        tmp[0][it] = v;
    }

    #pragma unroll
    for (int c = 0; c < CH; ++c) {
        if (c) __syncthreads();
        // write current chunk regs -> LDS
        #pragma unroll
        for (int it = 0; it < ITER; ++it) {
            int i = it * 256 + tid;
            if (i < POS * 4) *(short8*)(smem + (size_t)i * 16) = tmp[c % NBUF][it];
        }
        __syncthreads();
        // issue next chunk's global loads (latency hides under this chunk's MFMAs)
        if (c + 1 < CH) {
            #pragma unroll
            for (int it = 0; it < ITER; ++it) {
                int i = it * 256 + tid;
                short8 v = {0, 0, 0, 0, 0, 0, 0, 0};
                if (i < POS * 4 && (c + 1) * 32 + (i & 3) * 8 < KRLOC)
                    v = *(const short8*)(inN + goff[it] + (c + 1) * 64);
                tmp[(c + 1) % NBUF][it] = v;
            }
        }
        // compute chunk c
        const unsigned short* bc = Bt + (size_t)(c * 27) * NCO * 32 + (size_t)q * 32 + g * 8;
        #pragma unroll
        for (int t = 0; t < 27; ++t) {
            const int kz = t / 9, ky = (t / 3) % 3, kx = t % 3;
            const int toff = ((kz * (TY + 2) + ky) * XE + kx) * 64 + g * 16;
            short8 bq[NT];
            #pragma unroll
            for (int nt = 0; nt < NT; ++nt)
                bq[nt] = *(const short8*)(bc + ((size_t)t * NCO + nt * 16) * 32);
            #pragma unroll
            for (int j = 0; j < NSUB; ++j) {
                short8 a = *(const short8*)(smem + posj[j] * 64 + toff);
                #pragma unroll
                for (int nt = 0; nt < NT; ++nt)
                    acc[j][nt] = __builtin_amdgcn_mfma_f32_16x16x32_bf16(a, bq[nt], acc[j][nt], 0, 0, 0);
            }
        }
    }

    unsigned short* outN = out + (size_t)n * outNS;
    #pragma unroll
    for (int j = 0; j < NSUB; ++j) {
        int s = wv * NSUB + j;
        int sz = s / (TY * XG);
        int rm = s - sz * (TY * XG);
        int sy = rm / XG;
        int sxg = rm - sy * XG;
        int z = z0 + sz, y = y0 + sy;
        if (z < OUTD && y < OUTD) {
            #pragma unroll
            for (int rr = 0; rr < 4; ++rr) {
                int x = sxg * 16 + g * 4 + rr;
                if (x < OUTD) {
                    size_t ob = ((size_t)((z + OPAD) * OD2 + y + OPAD) * OD2 + (x + OPAD)) * OCST + OCOFF;
                    #pragma unroll
                    for (int nt = 0; nt < NT; ++nt) {
                        float v = acc[j][nt][rr] * BNS;
                        if (RELU) v = v > 0.f ? v : 0.f;
                        outN[ob + nt * 16 + q] = f2bf(v);
                    }
                }
            }
        }
    }
}

// ---------------- fused upc+ts2 at R9 tiling + T14 prefetch ----------------
// chunk0 (ci0..31) x Bupc -> co0..31 (NT=2); chunk1 (ci32..47 + zero pad) x Bts2 -> co32..47.
__global__ __launch_bounds__(256) void
k_cf(const unsigned short* __restrict__ in, const unsigned short* __restrict__ Bu,
     const unsigned short* __restrict__ Bts, unsigned short* __restrict__ out) {
    constexpr int TZ = 2, TY = 4, OUTD = 32, IND = 34, XE = 34, XG = 2;
    constexpr int NSUB = 4, ZT = 16, YT = 8;
    constexpr int POS = (TZ + 2) * (TY + 2) * XE;   // 816
    constexpr int ITER = (POS * 4 + 255) / 256;     // 13

    __shared__ __align__(16) unsigned char smem[POS * 64];

    int wg = xcd_swz(blockIdx.x, gridDim.x);
    int n = wg / (ZT * YT);
    int r0 = wg - n * (ZT * YT);
    int zt = r0 / YT, yt = r0 - zt * YT;
    int z0 = zt * TZ, y0 = yt * TY;

    int tid = threadIdx.x;
    int lane = tid & 63;
    int q = lane & 15, g = lane >> 4;
    int wv = tid >> 6;

    const unsigned char* inN = (const unsigned char*)(in + (size_t)n * U1);

    int goff[ITER];
    #pragma unroll
    for (int it = 0; it < ITER; ++it) {
        int i = it * 256 + tid;
        int i2 = i < POS * 4 ? i : POS * 4 - 1;
        int slot = i2 & 3;
        int pos = i2 >> 2;
        int dx = pos % XE;
        int rm = pos / XE;
        int dy = rm % (TY + 2);
        int dz = rm / (TY + 2);
        int iz = z0 + dz; iz = iz < IND - 1 ? iz : IND - 1;
        int iy = y0 + dy; iy = iy < IND - 1 ? iy : IND - 1;
        goff[it] = ((iz * IND + iy) * IND + dx) * 96 + slot * 16;
    }

    int posj[NSUB];
    #pragma unroll
    for (int j = 0; j < NSUB; ++j) {
        int s = wv * NSUB + j;
        int sz = s / (TY * XG);
        int rm = s - sz * (TY * XG);
        int sy = rm / XG;
        int sxg = rm - sy * XG;
        int x = sxg * 16 + q;
        x = x < OUTD ? x : OUTD - 1;
        posj[j] = (sz * (TY + 2) + sy) * XE + x;
    }

    f32x4 accU[NSUB][2];
    f32x4 accT[NSUB];
    #pragma unroll
    for (int j = 0; j < NSUB; ++j) {
        #pragma unroll
        for (int rr = 0; rr < 4; ++rr) {
            accU[j][0][rr] = 0.f; accU[j][1][rr] = 0.f; accT[j][rr] = 0.f;
        }
    }

    short8 tmp[2][ITER];
    #pragma unroll
    for (int it = 0; it < ITER; ++it) {
        int i = it * 256 + tid;
        short8 v = {0, 0, 0, 0, 0, 0, 0, 0};
        if (i < POS * 4 && (i & 3) * 8 < 48)
            v = *(const short8*)(inN + goff[it]);
        tmp[0][it] = v;
    }

    #pragma unroll
    for (int c = 0; c < 2; ++c) {
        if (c) __syncthreads();
        #pragma unroll
        for (int it = 0; it < ITER; ++it) {
            int i = it * 256 + tid;
            if (i < POS * 4) *(short8*)(smem + (size_t)i * 16) = tmp[c][it];
        }
        __syncthreads();
        if (c == 0) {
            // prefetch chunk 1 (ci32..47; slots 2,3 zero)
            #pragma unroll
            for (int it = 0; it < ITER; ++it) {
                int i = it * 256 + tid;
                short8 v = {0, 0, 0, 0, 0, 0, 0, 0};
                if (i < POS * 4 && 32 + (i & 3) * 8 < 48)
                    v = *(const short8*)(inN + goff[it] + 64);
                tmp[1][it] = v;
            }
            const unsigned short* bc = Bu + (size_t)q * 32 + g * 8;
            #pragma unroll
            for (int t = 0; t < 27; ++t) {
                const int kz = t / 9, ky = (t / 3) % 3, kx = t % 3;
                const int toff = ((kz * (TY + 2) + ky) * XE + kx) * 64 + g * 16;
                short8 b0 = *(const short8*)(bc + ((size_t)t * 32) * 32);
                short8 b1 = *(const short8*)(bc + ((size_t)t * 32 + 16) * 32);
                #pragma unroll
                for (int j = 0; j < NSUB; ++j) {
                    short8 a = *(const short8*)(smem + posj[j] * 64 + toff);
                    accU[j][0] = __builtin_amdgcn_mfma_f32_16x16x32_bf16(a, b0, accU[j][0], 0, 0, 0);
                    accU[j][1] = __builtin_amdgcn_mfma_f32_16x16x32_bf16(a, b1, accU[j][1], 0, 0, 0);
                }
            }
        } else {
            const unsigned short* bc = Bts + (size_t)q * 32 + g * 8;
            #pragma unroll
            for (int t = 0; t < 27; ++t) {
                const int kz = t / 9, ky = (t / 3) % 3, kx = t % 3;
                const int toff = ((kz * (TY + 2) + ky) * XE + kx) * 64 + g * 16;
                short8 b0 = *(const short8*)(bc + ((size_t)t * 16) * 32);
                #pragma unroll
                for (int j = 0; j < NSUB; ++j) {
                    short8 a = *(const short8*)(smem + posj[j] * 64 + toff);
                    accT[j] = __builtin_amdgcn_mfma_f32_16x16x32_bf16(a, b0, accT[j], 0, 0, 0);
                }
            }
        }
    }

    unsigned short* outN = out + (size_t)n * U2;
    #pragma unroll
    for (int j = 0; j < NSUB; ++j) {
        int s = wv * NSUB + j;
        int sz = s / (TY * XG);
        int rm = s - sz * (TY * XG);
        int sy = rm / XG;
        int sxg = rm - sy * XG;
        int z = z0 + sz, y = y0 + sy;
        if (z < OUTD && y < OUTD) {
            #pragma unroll
            for (int rr = 0; rr < 4; ++rr) {
                int x = sxg * 16 + g * 4 + rr;
                if (x < OUTD) {
                    size_t ob = ((size_t)((z + 2) * 36 + y + 2) * 36 + (x + 2)) * 48;
                    outN[ob + q]      = f2bf(accU[j][0][rr] * BNS);
                    outN[ob + 16 + q] = f2bf(accU[j][1][rr] * BNS);
                    outN[ob + 32 + q] = f2bf(accT[j][rr] * BNS);
                }
            }
        }
    }
}

// ---------------- replicate-pad shell fill for padded buf2 (36^3 x 48ch) ----------------
__global__ __launch_bounds__(256) void k_pad(unsigned short* __restrict__ buf2, int ncnt) {
    int i = blockIdx.x * 256 + threadIdx.x;
    int total = ncnt * 46656 * 6;
    if (i >= total) return;
    int slot = i % 6;
    int pos = (i / 6) % 46656;
    int nl = i / (6 * 46656);
    int x = pos % 36, y = (pos / 36) % 36, z = pos / 1296;
    if (x >= 2 && x < 34 && y >= 2 && y < 34 && z >= 2 && z < 34) return;
    int sx = x < 2 ? 2 : (x > 33 ? 33 : x);
    int sy = y < 2 ? 2 : (y > 33 ? 33 : y);
    int sz = z < 2 ? 2 : (z > 33 ? 33 : z);
    int src = (sz * 36 + sy) * 36 + sx;
    unsigned short* bn = buf2 + (size_t)nl * U2;
    *(u32x4*)(bn + (size_t)pos * 48 + slot * 8) =
        *(const u32x4*)(bn + (size_t)src * 48 + slot * 8);
}

// ---------------- convT as MFMA (LDS-staged): prevT -> buf1 c0..31 ----
__global__ __launch_bounds__(192) void
k_cT(const unsigned short* __restrict__ prevT, const unsigned short* __restrict__ Bt,
     unsigned short* __restrict__ buf1, int nbase) {
    constexpr int XE = 19, YS = 5, S = 2 * YS * XE;
    constexpr int MT = 68;

    __shared__ __align__(16) unsigned char smem[S * 80];

    int n = blockIdx.z;
    int ng = nbase + n;
    int q = blockIdx.y;
    int px = q & 1, py = (q >> 1) & 1, pz = q >> 2;
    int bt = blockIdx.x;
    int yt = bt % 5, z = bt / 5;
    int ty0 = yt * 4;

    int tid = threadIdx.x;
    int lane = tid & 63;
    int g = lane >> 4;
    int wv = tid >> 6;

    int mb = wv * 32 + (lane & 15);
    int m0 = mb < MT ? mb : MT - 1;
    int m1 = (mb + 16) < MT ? (mb + 16) : MT - 1;
    int dy0 = m0 / 17, x0 = m0 - dy0 * 17;
    int dy1 = m1 / 17, x1 = m1 - dy1 * 17;
    int pb0 = (dy0 * XE + x0) * 80 + g * 16;
    int pb1 = (dy1 * XE + x1) * 80 + g * 16;

    const unsigned short* inN = prevT + (size_t)ng * 4096 * 32;

    for (int i = tid; i < S * 4; i += 192) {
        int pos = i >> 2, slot = i & 3;
        int dz = pos / (YS * XE);
        int rem = pos - dz * (YS * XE);
        int dyy = rem / XE;
        int ix = rem - dyy * XE;
        int iz = z - 1 + dz;
        int iy = ty0 - 1 + dyy;
        int ixx = ix - 1;
        u32x4 v = {0u, 0u, 0u, 0u};
        if ((unsigned)iz < 16u && (unsigned)iy < 16u && (unsigned)ixx < 16u) {
            v = *(const u32x4*)(inN + ((size_t)(iz * 16 + iy) * 16 + ixx) * 32 + slot * 8);
        }
        *(u32x4*)(smem + pos * 80 + slot * 16) = v;
    }
    __syncthreads();

    int kz0 = 1 - pz, ky0 = 1 - py, kx0 = 1 - px;

    f32x4 acc[2][2];
    #pragma unroll
    for (int s2 = 0; s2 < 2; ++s2)
        #pragma unroll
        for (int nt = 0; nt < 2; ++nt)
            #pragma unroll
            for (int rr = 0; rr < 4; ++rr) acc[s2][nt][rr] = 0.f;

    #pragma unroll
    for (int cz = 0; cz < 2; ++cz)
        #pragma unroll
        for (int cy = 0; cy < 2; ++cy)
            #pragma unroll
            for (int cx = 0; cx < 2; ++cx) {
                int toff = ((cz * YS + cy) * XE + cx) * 80;
                int tapg = (((kz0 + 2 * cz) * 4 + (ky0 + 2 * cy)) * 4 + (kx0 + 2 * cx));
                const unsigned short* bb =
                    Bt + ((size_t)tapg * 32 + (lane & 15)) * 32 + g * 8;
                short8 a0 = *(const short8*)(smem + pb0 + toff);
                short8 a1 = *(const short8*)(smem + pb1 + toff);
                #pragma unroll
                for (int nt = 0; nt < 2; ++nt) {
                    short8 bf = *(const short8*)(bb + (size_t)nt * 16 * 32);
                    acc[0][nt] = __builtin_amdgcn_mfma_f32_16x16x32_bf16(a0, bf, acc[0][nt], 0, 0, 0);
                    acc[1][nt] = __builtin_amdgcn_mfma_f32_16x16x32_bf16(a1, bf, acc[1][nt], 0, 0, 0);
                }
            }

    unsigned short* outN = buf1 + (size_t)n * U1;
    int co0 = lane & 15;
    #pragma unroll
    for (int sub = 0; sub < 2; ++sub) {
        #pragma unroll
        for (int rr = 0; rr < 4; ++rr) {
            int m = wv * 32 + sub * 16 + g * 4 + rr;
            if (m < MT) {
                int dy = m / 17, tx = m - dy * 17;
                if (ty0 + dy < 17) {
                    int oz = 2 * z + pz, oy = 2 * (ty0 + dy) + py, ox = 2 * tx + px;
                    size_t ob = ((size_t)(oz * 34 + oy) * 34 + ox) * 48;
                    #pragma unroll
                    for (int nt = 0; nt < 2; ++nt) {
                        float v = acc[sub][nt][rr] * BNS;
                        outN[ob + nt * 16 + co0] = f2bf(v > 0.f ? v : 0.f);
                    }
                }
            }
        }
    }
}

// ---------------- maxpool3 (pa out [30^3][16] bf16, region stride U2) -> P1 fp32 NCDHW ----
__global__ __launch_bounds__(256) void k_pool3(const unsigned short* __restrict__ pa,
                                               float* __restrict__ out,
                                               int nbase, int ncnt) {
    int i = blockIdx.x * 256 + threadIdx.x;
    if (i >= ncnt * 16000) return;
    int c = i & 15;
    int rest = i >> 4;
    int x = rest % 10;
    int y = (rest / 10) % 10;
    int z = (rest / 100) % 10;
    int nl = rest / 1000;
    const unsigned short* p = pa + (size_t)nl * U2;
    float m = -INFINITY;
    #pragma unroll
    for (int dz = 0; dz < 3; ++dz)
        #pragma unroll
        for (int dy = 0; dy < 3; ++dy)
            #pragma unroll
            for (int dx = 0; dx < 3; ++dx)
                m = fmaxf(m, bf2f(p[((size_t)((3 * z + dz) * 30 + 3 * y + dy) * 30 +
                                    (3 * x + dx)) * 16 + c]));
    out[((size_t)(nbase + nl) * 16 + c) * 1000 + (z * 100 + y * 10 + x)] = m;
}

// ---------------- small fp32 conv for pb ----------------
template <int CIN, int COUT, int IND, int OUTD>
__global__ __launch_bounds__(256) void k_conv3(const float* __restrict__ in,
                                               const float* __restrict__ wT,
                                               float* __restrict__ out) {
    constexpr int IN3 = IND * IND * IND;
    constexpr int OD3 = OUTD * OUTD * OUTD;
    int n = blockIdx.y;
    int s = blockIdx.x * 256 + threadIdx.x;
    if (s >= OD3) return;
    int z = s / (OUTD * OUTD);
    int r = s % (OUTD * OUTD);
    int y = r / OUTD;
    int x = r % OUTD;

    int offs[27];
    #pragma unroll
    for (int kz = 0; kz < 3; ++kz)
        #pragma unroll
        for (int ky = 0; ky < 3; ++ky)
            #pragma unroll
            for (int kx = 0; kx < 3; ++kx)
                offs[(kz * 3 + ky) * 3 + kx] = ((z + kz) * IND + y + ky) * IND + x + kx;

    float acc[COUT];
    #pragma unroll
    for (int c = 0; c < COUT; ++c) acc[c] = 0.f;

    const float* inN = in + (size_t)n * CIN * IN3;
    for (int ci = 0; ci < CIN; ++ci) {
        const float* pc = inN + (size_t)ci * IN3;
        const float* wci = wT + ci * 27 * COUT;
        #pragma unroll
        for (int t = 0; t < 27; ++t) {
            float v = pc[offs[t]];
            const float* wp = wci + t * COUT;
            #pragma unroll
            for (int co = 0; co < COUT; ++co) acc[co] = fmaf(v, wp[co], acc[co]);
        }
    }

    float* o = out + (size_t)n * COUT * OD3 + s;
    #pragma unroll
    for (int co = 0; co < COUT; ++co) {
        float v = acc[co] * BNS;
        o[(size_t)co * OD3] = v > 0.f ? v : 0.f;
    }
}

// ---------------- maxpool4 + linear + softmax + threshold ----------------
__global__ __launch_bounds__(64) void k_final(const float* __restrict__ p2,
                                              const float* __restrict__ wlin,
                                              const float* __restrict__ blin,
                                              float* __restrict__ dout) {
    int n = blockIdx.x;
    int t = threadIdx.x;
    int c = t >> 3, dz = (t >> 2) & 1, dy = (t >> 1) & 1, dx = t & 1;
    const float* p = p2 + ((size_t)n * 8 + c) * 512;
    float m = -INFINITY;
    #pragma unroll
    for (int iz = 0; iz < 4; ++iz)
        #pragma unroll
        for (int iy = 0; iy < 4; ++iy)
            #pragma unroll
            for (int ix = 0; ix < 4; ++ix)
                m = fmaxf(m, p[((dz * 4 + iz) * 8 + dy * 4 + iy) * 8 + dx * 4 + ix]);
    __shared__ float h[64];
    __shared__ float lg[3];
    h[t] = m;
    __syncthreads();
    if (t < 3) {
        float acc = blin[t];
        for (int k = 0; k < 64; ++k) acc += h[k] * wlin[t * 64 + k];
        lg[t] = acc;
    }
    __syncthreads();
    if (t == 0) {
        float mx = fmaxf(fmaxf(lg[0], lg[1]), lg[2]);
        float e0 = expf(lg[0] - mx), e1 = expf(lg[1] - mx), e2 = expf(lg[2] - mx);
        float inv = 1.f / (e0 + e1 + e2);
        dout[n * 3 + 0] = e0 * inv;
        dout[n * 3 + 1] = e1 * inv;
        dout[n * 3 + 2] = e2 * inv;
        dout[81 + n] = (e2 * inv) > 0.1f ? 1.0f : 0.0f;
    }
}

extern "C" void kernel_launch(void* const* d_in, const int* in_sizes, int n_in,
                              void* d_out, int out_size, void* d_ws, size_t ws_size,
                              hipStream_t stream) {
    const float* tsdf  = (const float*)d_in[0];
    const float* prev  = (const float*)d_in[1];
    const float* w_upt = (const float*)d_in[2];
    const float* w_upc = (const float*)d_in[3];
    const float* w_ts1 = (const float*)d_in[4];
    const float* w_ts2 = (const float*)d_in[5];
    const float* w_b1a = (const float*)d_in[6];
    const float* w_b1b = (const float*)d_in[7];
    const float* w_pa  = (const float*)d_in[8];
    const float* w_pb  = (const float*)d_in[9];
    const float* w_lin = (const float*)d_in[10];
    const float* b_lin = (const float*)d_in[11];
    float* dout = (float*)d_out;

    char* base = (char*)d_ws;
    size_t off = 0;
    auto alB = [&](size_t bytes) {
        off = (off + 255) & ~(size_t)255;
        void* p = base + off;
        off += bytes;
        return p;
    };

    float* P1      = (float*)alB((size_t)27 * 16 * 1000 * 4);
    float* P2      = (float*)alB((size_t)27 * 8 * 512 * 4);
    float* wT_ts1  = (float*)alB(27 * 16 * 4);
    float* wT_pb   = (float*)alB((size_t)16 * 27 * 8 * 4);
    unsigned short* prevT   = (unsigned short*)alB((size_t)27 * 4096 * 32 * 2);
    unsigned short* BtT_upt = (unsigned short*)alB((size_t)64 * 32 * 32 * 2);
    unsigned short* Bt_upc  = (unsigned short*)alB((size_t)27 * 32 * 32 * 2);
    unsigned short* Bt_ts2  = (unsigned short*)alB((size_t)27 * 16 * 32 * 2);
    unsigned short* Bt_b1a  = (unsigned short*)alB((size_t)2 * 27 * 32 * 32 * 2);
    unsigned short* Bt_b1b  = (unsigned short*)alB((size_t)27 * 32 * 32 * 2);
    unsigned short* Bt_pa   = (unsigned short*)alB((size_t)27 * 16 * 32 * 2);

    size_t fixed = (off + 255) & ~(size_t)255;
    size_t per_block = (U1 + U2 + U3) * 2 + 768;
    size_t avail = ws_size > fixed ? ws_size - fixed : 0;
    int NB = (int)(avail / per_block);
    if (NB > 27) NB = 27;
    if (NB < 1) NB = 1;

    unsigned short* buf1 = (unsigned short*)alB((size_t)NB * U1 * 2);
    unsigned short* buf2 = (unsigned short*)alB((size_t)NB * U2 * 2);
    unsigned short* buf3 = (unsigned short*)alB((size_t)NB * U3 * 2);

    // fused weight prep (one launch) + prev transpose
    k_prep<<<cdiv(207664, 256), 256, 0, stream>>>(
        w_upt, w_upc, w_ts2, w_b1a, w_b1b, w_pa, w_ts1, w_pb,
        BtT_upt, Bt_upc, Bt_ts2, Bt_b1a, Bt_b1b, Bt_pa, wT_ts1, wT_pb);
    k_tprev<<<dim3(64, 27), 256, 0, stream>>>(prev, prevT);

    for (int n0 = 0; n0 < 27; n0 += NB) {
        int nc = 27 - n0 < NB ? 27 - n0 : NB;

        // producers into buf1 [34^3][48]
        k_cT<<<dim3(17 * 5, 8, nc), 192, 0, stream>>>(prevT, BtT_upt, buf1, n0);
        k_ts1<<<dim3(cdiv(39304, 256), nc), 256, 0, stream>>>(tsdf, wT_ts1, buf1, n0);

        // fused upc+ts2 into padded buf2 interior [36^3][48] at +2
        k_cf<<<nc * 16 * 8, 256, 0, stream>>>(buf1, Bt_upc, Bt_ts2, buf2);

        // replicate-pad shell of buf2
        k_pad<<<cdiv(nc * 46656 * 6, 256), 256, 0, stream>>>(buf2, nc);

        // b1a: padded buf2 (48ch, relu) -> buf3 [34^3][32]
        k_cl<48, 0, 48, 2, 32, 32, 0, 36, 34, 34, 0, true>
            <<<nc * 17 * 9, 256, 0, stream>>>(buf2, Bt_b1a, buf3, U2, U3);

        // b1b: buf3 -> feat [32^3][32] (into buf1 region)
        k_cl<32, 0, 32, 1, 32, 32, 0, 34, 32, 32, 0, false>
            <<<nc * 16 * 8, 256, 0, stream>>>(buf3, Bt_b1b, buf1, U3, U1);

        // pa: feat -> [30^3][16] (into buf2 region), relu
        k_cl<32, 0, 32, 1, 16, 16, 0, 32, 30, 30, 0, true>
            <<<nc * 15 * 8, 256, 0, stream>>>(buf1, Bt_pa, buf2, U1, U2);

        // pool3 into global P1 (fp32 NCDHW)
        k_pool3<<<cdiv(nc * 16000, 256), 256, 0, stream>>>(buf2, P1, n0, nc);
    }

    // tail
    k_conv3<16, 8, 10, 8><<<dim3(cdiv(512, 256), 27), 256, 0, stream>>>(P1, wT_pb, P2);
    k_final<<<27, 64, 0, stream>>>(P2, w_lin, b_lin, dout);
}